// Round 9
// baseline (199.849 us; speedup 1.0000x reference)
//
#include <hip/hip_runtime.h>
#include <math.h>

// ============================================================================
// Attention block (B=8, C=512, H=W=32, nh=8, hd=64) via bf16 MFMA + fp32-ish
// precision where it matters.  Round 19:
//  - attn: P-LDS round trip was the uncovered critical path (S-MFMA -> exp ->
//    pack -> ds_write -> lgkmcnt -> ds_read -> PV with nothing overlapping).
//    Restructured: S computed in Mt-HALF phases (A: Mt0,1; B: Mt2,3), PV(ks=1)
//    ROTATED into the next iteration.  Every ds_read now issues beside a
//    16-MFMA cluster; no new register state (peak ~224 <= 256 @ 2 waves/EU;
//    launch_bounds stays (256,2) per the r13/r17 hard rule).
//  - gemm_proj: was 256 blocks = 1 block/CU -> barrier drains fully exposed.
//    Retiled 64x128 (M x N), grid (8,8,8) = 512 blocks = 2/CU.
//  - r18 carried: single x single bf16 everywhere (wq,wp,x single RNE planes),
//    bare v_exp_f32, deferred l-reduce, K/V same-reg prefetch, setprio, exp2
//    domain, cvt_pk packs, XCD swizzle, fused prep.
// ============================================================================

typedef unsigned int u32;
typedef float  f32x4 __attribute__((ext_vector_type(4)));
typedef short  s16x8 __attribute__((ext_vector_type(8)));
typedef unsigned short u16x4 __attribute__((ext_vector_type(4)));
typedef unsigned int   u32x2 __attribute__((ext_vector_type(2)));
typedef unsigned int   u32x4 __attribute__((ext_vector_type(4)));

#define MFMA16(a, b, c) __builtin_amdgcn_mfma_f32_16x16x32_bf16(a, b, c, 0, 0, 0)

__device__ __forceinline__ ushort f2bf(float f) {  // RNE fp32->bf16 (scalar)
    u32 b = __float_as_uint(f);
    return (ushort)((b + 0x7FFFu + ((b >> 16) & 1u)) >> 16);
}
__device__ __forceinline__ float bf2f(ushort v) {
    return __uint_as_float(((u32)v) << 16);
}
// packed RNE fp32x2 -> bf16x2 (low16 = a, high16 = b)
__device__ __forceinline__ u32 cvtpk(float a, float b) {
    u32 r;
    asm("v_cvt_pk_bf16_f32 %0, %1, %2" : "=v"(r) : "v"(a), "v"(b));
    return r;
}

// ---------------------------------------------------------------------------
// prep: fused weight-convert + x transpose.
// ---------------------------------------------------------------------------
__global__ __launch_bounds__(256) void prep(
    const float* __restrict__ x, const float* __restrict__ wq,
    const float* __restrict__ wp, ushort* __restrict__ xh,
    ushort* __restrict__ wq_s, ushort* __restrict__ wp_s) {
    __shared__ __align__(16) ushort Th[64 * 72];
    const int t = threadIdx.x;

    // --- weight chunk (independent of x work; hides under LDS phase)
    {
        const int id = (blockIdx.z * 8 + blockIdx.y) * 16 + blockIdx.x;
        size_t base = ((size_t)id * 256 + t) * 4;
        const float* src; ushort* dst; size_t off;
        if (base < 786432) { src = wq; dst = wq_s; off = base; }
        else               { src = wp; dst = wp_s; off = base - 786432; }
        f32x4 v = *(const f32x4*)(src + off);
        u16x4 s;
#pragma unroll
        for (int e = 0; e < 4; e++) s[e] = f2bf(v[e]);
        *(u16x4*)(dst + off) = s;
    }

    // --- x transpose tile
    const int n0 = blockIdx.x * 64, c0 = blockIdx.y * 64, b = blockIdx.z;
    const int c = t >> 2, nseg = (t & 3) * 4;
    const float* src = x + ((size_t)b * 512 + c0 + c) * 1024 + n0;
#pragma unroll
    for (int i = 0; i < 4; i++) {
        f32x4 v = *(const f32x4*)(src + nseg + i * 16);
#pragma unroll
        for (int e = 0; e < 4; e++) {
            int nl = nseg + i * 16 + e;
            Th[nl * 72 + c] = f2bf(v[e]);
        }
    }
    __syncthreads();
#pragma unroll
    for (int i = 0; i < 2; i++) {
        int nl = i * 32 + (t >> 3);
        int u = t & 7;
        s16x8 vh = *(const s16x8*)(Th + nl * 72 + u * 8);
        size_t go = ((size_t)b * 1024 + n0 + nl) * 512 + c0 + u * 8;
        *(s16x8*)(xh + go) = vh;
    }
}

// ---------------------------------------------------------------------------
// single x single bf16 GEMM mainloop: 128x128 tile, BK=32, 1 MFMA/tile.
// smem needs 10240 ushorts (20,480 B).  Used by gemm_qkv.
// ---------------------------------------------------------------------------
__device__ __forceinline__ void gemm_core1(
    const ushort* __restrict__ A_g, int arow0,
    const ushort* __restrict__ B_g, size_t brow0,
    ushort* smem, f32x4 (&acc)[4][4]) {
    const int t = threadIdx.x;
    ushort* As = smem;
    ushort* Bs = smem + 5120;
    const int ro = t >> 1, cs = (t & 1) << 4;
    const size_t ga = (size_t)(arow0 + ro) * 512 + cs;
    const size_t gb = (brow0 + ro) * 512 + cs;
    const int l15 = t & 15, quad = (t >> 4) & 3, wv = t >> 6;
    const int lra = (((wv >> 1) * 64) + l15) * 40 + quad * 8;
    const int lrb = (((wv & 1) * 64) + l15) * 40 + quad * 8;
    const int lw = ro * 40 + cs;

    s16x8 va0 = *(const s16x8*)(A_g + ga), va1 = *(const s16x8*)(A_g + ga + 8);
    s16x8 vb0 = *(const s16x8*)(B_g + gb), vb1 = *(const s16x8*)(B_g + gb + 8);

    for (int k0 = 0; k0 < 512; k0 += 32) {
        __syncthreads();
        *(s16x8*)(As + lw) = va0; *(s16x8*)(As + lw + 8) = va1;
        *(s16x8*)(Bs + lw) = vb0; *(s16x8*)(Bs + lw + 8) = vb1;
        const int kn = (k0 + 32) & 511;  // wraps to 0 on last iter (discarded)
        va0 = *(const s16x8*)(A_g + ga + kn); va1 = *(const s16x8*)(A_g + ga + kn + 8);
        vb0 = *(const s16x8*)(B_g + gb + kn); vb1 = *(const s16x8*)(B_g + gb + kn + 8);
        __syncthreads();
        s16x8 a[4], bb[4];
#pragma unroll
        for (int Mt = 0; Mt < 4; Mt++)
            a[Mt] = *(const s16x8*)(As + lra + Mt * 640);
#pragma unroll
        for (int Nt = 0; Nt < 4; Nt++)
            bb[Nt] = *(const s16x8*)(Bs + lrb + Nt * 640);
#pragma unroll
        for (int Mt = 0; Mt < 4; Mt++)
#pragma unroll
            for (int Nt = 0; Nt < 4; Nt++)
                acc[Mt][Nt] = MFMA16(a[Mt], bb[Nt], acc[Mt][Nt]);
    }
    __syncthreads();  // LDS free for epilogue reuse
}

// ---------------------------------------------------------------------------
// QKV GEMM (single x single).  Unchanged from r18.
// ---------------------------------------------------------------------------
__global__ __launch_bounds__(256) void gemm_qkv(
    const ushort* __restrict__ wq_s, const ushort* __restrict__ xt_h,
    ushort* __restrict__ qT, ushort* __restrict__ kT, ushort* __restrict__ vT) {
    __shared__ __align__(16) ushort smem[10240];
    f32x4 acc[4][4];
#pragma unroll
    for (int i = 0; i < 4; i++)
#pragma unroll
        for (int j = 0; j < 4; j++) acc[i][j] = (f32x4)0.0f;

    const int n0 = blockIdx.x * 128, o0 = blockIdx.y * 128, bz = blockIdx.z;
    gemm_core1(wq_s, o0, xt_h, (size_t)bz * 1024 + n0, smem, acc);

    const int t = threadIdx.x;
    const int l15 = t & 15, quad = (t >> 4) & 3, wv = t >> 6, lane = t & 63;
    const int g = blockIdx.y * 2 + (wv >> 1);
    const int role = g % 3, head = g / 3;
    const int nh = (wv & 1) * 64;
    const size_t hb = (size_t)bz * 8 + head;
    // Q scale folds attn's 1/sqrt(64) AND log2(e) so attn can use bare exp2.
    const float scale = (role == 0) ? 0.18033688011112042f : 1.0f;

    if (role < 2) {
        ushort* dst = (role == 0) ? qT : kT;
        ushort* T = smem + wv * 2304;                // per-wave [64 n][36] ushort
        const size_t rowbase = hb * 1024 + n0 + nh;  // pixel row index
#pragma unroll
        for (int sp = 0; sp < 2; sp++) {
#pragma unroll
            for (int Mti = 0; Mti < 2; Mti++)
#pragma unroll
                for (int Nt = 0; Nt < 4; Nt++) {
                    f32x4 v = acc[sp * 2 + Mti][Nt];
                    u32x2 pk;
                    pk.x = cvtpk(v[0] * scale, v[1] * scale);
                    pk.y = cvtpk(v[2] * scale, v[3] * scale);
                    *(u32x2*)(T + (Nt * 16 + l15) * 36 + Mti * 16 + quad * 4) = pk;
                }
            asm volatile("s_waitcnt lgkmcnt(0)" ::: "memory");
#pragma unroll
            for (int i = 0; i < 8; i++) {
                int nl = i * 8 + (lane >> 3);
                u16x4 vv = *(const u16x4*)(T + nl * 36 + (lane & 7) * 4);
                *(u16x4*)(dst + (rowbase + nl) * 64 + sp * 32 + (lane & 7) * 4) = vv;
            }
            asm volatile("s_waitcnt lgkmcnt(0)" ::: "memory");
        }
    } else {
        const size_t vb2 = hb * 64 * 1024 + (size_t)(n0 + nh);
#pragma unroll
        for (int Mt = 0; Mt < 4; Mt++)
#pragma unroll
            for (int Nt = 0; Nt < 4; Nt++)
#pragma unroll
                for (int r = 0; r < 4; r++)
                    vT[vb2 + (size_t)(Mt * 16 + quad * 4 + r) * 1024 + Nt * 16 + l15] =
                        f2bf(acc[Mt][Nt][r]);
    }
}

// ---------------------------------------------------------------------------
// Proj GEMM: 64x128 (MxN) tiles, grid (8,8,8) = 512 blocks = 2 blocks/CU
// (was 256 = 1/CU with fully-exposed barrier drains).  Per wave acc[4][2];
// waves split N 4 ways (wv*32).  LDS: A 64x40 + B 128x40 = 15,360 B.
// ---------------------------------------------------------------------------
__global__ __launch_bounds__(256) void gemm_proj(
    const ushort* __restrict__ wp_s, const ushort* __restrict__ ht,
    const float* __restrict__ bias, float* __restrict__ out) {
    __shared__ __align__(16) ushort smem[7680];
    ushort* As = smem;          // [64][40]
    ushort* Bs = smem + 2560;   // [128][40]
    f32x4 acc[4][2];
#pragma unroll
    for (int i = 0; i < 4; i++)
#pragma unroll
        for (int j = 0; j < 2; j++) acc[i][j] = (f32x4)0.0f;

    const int n0 = blockIdx.x * 128, o0 = blockIdx.y * 64, bz = blockIdx.z;
    const int t = threadIdx.x;
    const int roa = t >> 2, csa = (t & 3) * 8;      // A: 64 rows x 32 k
    const size_t ga = (size_t)(o0 + roa) * 512 + csa;
    const int rob = t >> 1, csb = (t & 1) << 4;     // B: 128 rows x 32 k
    const size_t gb = ((size_t)bz * 1024 + n0 + rob) * 512 + csb;
    const int l15 = t & 15, quad = (t >> 4) & 3, wv = t >> 6;
    const int lra = l15 * 40 + quad * 8;
    const int lrb = (wv * 32 + l15) * 40 + quad * 8;
    const int lwa = roa * 40 + csa;
    const int lwb = rob * 40 + csb;

    s16x8 va  = *(const s16x8*)(wp_s + ga);
    s16x8 vb0 = *(const s16x8*)(ht + gb), vb1 = *(const s16x8*)(ht + gb + 8);

    for (int k0 = 0; k0 < 512; k0 += 32) {
        __syncthreads();
        *(s16x8*)(As + lwa) = va;
        *(s16x8*)(Bs + lwb) = vb0; *(s16x8*)(Bs + lwb + 8) = vb1;
        const int kn = (k0 + 32) & 511;  // wraps to 0 on last iter (discarded)
        va  = *(const s16x8*)(wp_s + ga + kn);
        vb0 = *(const s16x8*)(ht + gb + kn); vb1 = *(const s16x8*)(ht + gb + kn + 8);
        __syncthreads();
        s16x8 a[4], bb[2];
#pragma unroll
        for (int Mt = 0; Mt < 4; Mt++)
            a[Mt] = *(const s16x8*)(As + lra + Mt * 640);
#pragma unroll
        for (int Nt = 0; Nt < 2; Nt++)
            bb[Nt] = *(const s16x8*)(Bs + lrb + Nt * 640);
#pragma unroll
        for (int Mt = 0; Mt < 4; Mt++)
#pragma unroll
            for (int Nt = 0; Nt < 2; Nt++)
                acc[Mt][Nt] = MFMA16(a[Mt], bb[Nt], acc[Mt][Nt]);
    }

#pragma unroll
    for (int Mt = 0; Mt < 4; Mt++)
#pragma unroll
        for (int Nt = 0; Nt < 2; Nt++) {
            int ob = o0 + Mt * 16 + quad * 4;
            int nn = n0 + wv * 32 + Nt * 16 + l15;
#pragma unroll
            for (int r = 0; r < 4; r++)
                out[((size_t)bz * 512 + ob + r) * 1024 + nn] = acc[Mt][Nt][r] + bias[ob + r];
        }
}

// ---------------------------------------------------------------------------
// Flash attention, round 19: 64-query blocks, wave-split keys, in-block
// combine.  S computed in Mt-HALF phases; PV(ks=1) rotated into the next
// iteration so every P-LDS read issues beside a 16-MFMA cluster:
//   [pf1 reads ~ phase-A MFMA] -> PV1(prev) -> expA/packA(cols 0..31) ->
//   phase-B MFMA -> Kpref -> PV0(cols 0..31) -> vf0 pref -> expB/packB.
// launch_bounds (256,2): peak liveness ~224 regs (hard rule: never above
// proven VGPR).  Grid 1024 blocks; LDS Pw 4x[64][68] + Ls 1KB.
// ---------------------------------------------------------------------------
__global__ __launch_bounds__(256, 2) void attn_mfma(
    const ushort* __restrict__ qT, const ushort* __restrict__ kT,
    const ushort* __restrict__ vT, ushort* __restrict__ ht) {
    __shared__ __align__(16) ushort Ps[4 * 4352];  // per-wave [64 q][68]
    __shared__ float Ls[4][64];
    const int t = threadIdx.x;
    // XCD swizzle: 8 consecutive bh per XCD -> 2MB K/V slice L2-resident.
    const int id = blockIdx.x + (blockIdx.y << 4);
    const int swz = (id & 7) * 128 + (id >> 3);
    const int qt = swz & 15, bh = swz >> 4;
    const int b = bh >> 3, h = bh & 7;
    const int m0 = qt * 64;
    const int l15 = t & 15, quad = (t >> 4) & 3, wv = t >> 6;

    // All 64 block-queries in registers: 4 q-tiles x 2 ks (single bf16)
    s16x8 qf[4][2];
#pragma unroll
    for (int Nt = 0; Nt < 4; Nt++) {
        const size_t qb = ((size_t)bh * 1024 + m0 + Nt * 16 + l15) * 64 + quad * 8;
        qf[Nt][0] = *(const s16x8*)(qT + qb);
        qf[Nt][1] = *(const s16x8*)(qT + qb + 32);
    }

    f32x4 O[4][4];  // [Mt: d-tile][Nt: q-tile]
#pragma unroll
    for (int i = 0; i < 4; i++)
#pragma unroll
        for (int j = 0; j < 4; j++) O[i][j] = (f32x4)0.0f;
    float lrun[4] = {0.f, 0.f, 0.f, 0.f};

    const ushort* kb = kT + (size_t)bh * 65536;
    const ushort* vb = vT + (size_t)bh * 65536;
    ushort* Pw = Ps + wv * 4352;

    // Prologue: K (both ks) and V (both halves) for tile 0
    s16x8 kf[2][4], vf[2][4];
    {
        const int kt = wv * 4;
        const size_t kbase = (size_t)kt * 4096 + l15 * 64 + quad * 8;
        const size_t vbase = (size_t)l15 * 1024 + kt * 64 + quad * 8;
#pragma unroll
        for (int ks = 0; ks < 2; ks++)
#pragma unroll
            for (int Mt = 0; Mt < 4; Mt++) {
                kf[ks][Mt] = *(const s16x8*)(kb + kbase + Mt * 1024 + ks * 32);
                vf[ks][Mt] = *(const s16x8*)(vb + vbase + Mt * 16384 + ks * 32);
            }
    }

#pragma unroll 1
    for (int i = 0; i < 4; i++) {
        const int ktn = wv * 4 + i + 1;  // next wave-private key tile

        // ---- Phase A: S for Mt=0,1 (all 4 q-tiles) -- 16 MFMA
        f32x4 SA[2][4];
#pragma unroll
        for (int m = 0; m < 2; m++)
#pragma unroll
            for (int qa = 0; qa < 4; qa++) SA[m][qa] = (f32x4)0.0f;
        __builtin_amdgcn_s_setprio(1);
#pragma unroll
        for (int ks = 0; ks < 2; ks++)
#pragma unroll
            for (int m = 0; m < 2; m++)
#pragma unroll
                for (int qa = 0; qa < 4; qa++)
                    SA[m][qa] = MFMA16(kf[ks][m], qf[qa][ks], SA[m][qa]);

        // ---- PV1 of PREVIOUS tile: ds_reads covered by phase-A MFMAs
        if (i > 0) {
            s16x8 pf1[4];
#pragma unroll
            for (int Nt = 0; Nt < 4; Nt++)
                pf1[Nt] = *(const s16x8*)(Pw + (Nt * 16 + l15) * 68 + 32 + quad * 8);
#pragma unroll
            for (int Mt = 0; Mt < 4; Mt++)
#pragma unroll
                for (int Nt = 0; Nt < 4; Nt++)
                    O[Mt][Nt] = MFMA16(vf[1][Mt], pf1[Nt], O[Mt][Nt]);
        }
        __builtin_amdgcn_s_setprio(0);

        // vf[1] of PREVIOUS tile now dead: load this tile's V second half
        if (i > 0) {
            const size_t vbase = (size_t)l15 * 1024 + (wv * 4 + i) * 64 + quad * 8;
#pragma unroll
            for (int Mt = 0; Mt < 4; Mt++)
                vf[1][Mt] = *(const s16x8*)(vb + vbase + Mt * 16384 + 32);
        }

        // ---- expA + lrun + packA (cols 0..31)
#pragma unroll
        for (int qa = 0; qa < 4; qa++) {
#pragma unroll
            for (int m = 0; m < 2; m++)
#pragma unroll
                for (int r = 0; r < 4; r++)
                    SA[m][qa][r] = __builtin_amdgcn_exp2f(SA[m][qa][r]);
            float s0 = (SA[0][qa][0] + SA[0][qa][1]) + (SA[0][qa][2] + SA[0][qa][3]);
            float s1 = (SA[1][qa][0] + SA[1][qa][1]) + (SA[1][qa][2] + SA[1][qa][3]);
            lrun[qa] += s0 + s1;
        }
#pragma unroll
        for (int qa = 0; qa < 4; qa++)
#pragma unroll
            for (int m = 0; m < 2; m++) {
                u32x2 pb;
                pb.x = cvtpk(SA[m][qa][0], SA[m][qa][1]);
                pb.y = cvtpk(SA[m][qa][2], SA[m][qa][3]);
                *(u32x2*)(Pw + (qa * 16 + l15) * 68 + m * 16 + quad * 4) = pb;
            }

        // ---- Phase B: S for Mt=2,3 -- covers PV0's ds_reads below
        f32x4 SB[2][4];
#pragma unroll
        for (int m = 0; m < 2; m++)
#pragma unroll
            for (int qa = 0; qa < 4; qa++) SB[m][qa] = (f32x4)0.0f;
        __builtin_amdgcn_s_setprio(1);
#pragma unroll
        for (int ks = 0; ks < 2; ks++)
#pragma unroll
            for (int m = 0; m < 2; m++)
#pragma unroll
                for (int qa = 0; qa < 4; qa++)
                    SB[m][qa] = MFMA16(kf[ks][m + 2], qf[qa][ks], SB[m][qa]);
        __builtin_amdgcn_s_setprio(0);

        // kf fully dead: prefetch next tile's K
        if (i < 3) {
            const size_t kbase = (size_t)ktn * 4096 + l15 * 64 + quad * 8;
#pragma unroll
            for (int ks = 0; ks < 2; ks++)
#pragma unroll
                for (int Mt = 0; Mt < 4; Mt++)
                    kf[ks][Mt] = *(const s16x8*)(kb + kbase + Mt * 1024 + ks * 32);
        }

        // ---- PV0 (cols 0..31, phase-A P; reads ride behind phase-B MFMAs)
        {
            s16x8 pf0[4];
#pragma unroll
            for (int Nt = 0; Nt < 4; Nt++)
                pf0[Nt] = *(const s16x8*)(Pw + (Nt * 16 + l15) * 68 + quad * 8);
            __builtin_amdgcn_s_setprio(1);
#pragma unroll
            for (int Mt = 0; Mt < 4; Mt++)
#pragma unroll
                for (int Nt = 0; Nt < 4; Nt++)
                    O[Mt][Nt] = MFMA16(vf[0][Mt], pf0[Nt], O[Mt][Nt]);
            __builtin_amdgcn_s_setprio(0);
        }

        // vf[0] dead: prefetch next tile's V first half
        if (i < 3) {
            const size_t vbase = (size_t)l15 * 1024 + ktn * 64 + quad * 8;
#pragma unroll
            for (int Mt = 0; Mt < 4; Mt++)
                vf[0][Mt] = *(const s16x8*)(vb + vbase + Mt * 16384);
        }

        // ---- expB + lrun + packB (cols 32..63) -- consumed next iter (PV1)
#pragma unroll
        for (int qa = 0; qa < 4; qa++) {
#pragma unroll
            for (int m = 0; m < 2; m++)
#pragma unroll
                for (int r = 0; r < 4; r++)
                    SB[m][qa][r] = __builtin_amdgcn_exp2f(SB[m][qa][r]);
            float s0 = (SB[0][qa][0] + SB[0][qa][1]) + (SB[0][qa][2] + SB[0][qa][3]);
            float s1 = (SB[1][qa][0] + SB[1][qa][1]) + (SB[1][qa][2] + SB[1][qa][3]);
            lrun[qa] += s0 + s1;
        }
#pragma unroll
        for (int qa = 0; qa < 4; qa++)
#pragma unroll
            for (int m = 0; m < 2; m++) {
                u32x2 pb;
                pb.x = cvtpk(SB[m][qa][0], SB[m][qa][1]);
                pb.y = cvtpk(SB[m][qa][2], SB[m][qa][3]);
                *(u32x2*)(Pw + (qa * 16 + l15) * 68 + (m + 2) * 16 + quad * 4) = pb;
            }
    }

    // Epilogue: PV1 of the last tile
    {
        s16x8 pf1[4];
#pragma unroll
        for (int Nt = 0; Nt < 4; Nt++)
            pf1[Nt] = *(const s16x8*)(Pw + (Nt * 16 + l15) * 68 + 32 + quad * 8);
        __builtin_amdgcn_s_setprio(1);
#pragma unroll
        for (int Mt = 0; Mt < 4; Mt++)
#pragma unroll
            for (int Nt = 0; Nt < 4; Nt++)
                O[Mt][Nt] = MFMA16(vf[1][Mt], pf1[Nt], O[Mt][Nt]);
        __builtin_amdgcn_s_setprio(0);
    }

    // Wave partials -> LDS (bf16 O over the dead P region; fp32 l).
#pragma unroll
    for (int Mt = 0; Mt < 4; Mt++)
#pragma unroll
        for (int Nt = 0; Nt < 4; Nt++) {
            u32x2 pk;
            pk.x = cvtpk(O[Mt][Nt][0], O[Mt][Nt][1]);
            pk.y = cvtpk(O[Mt][Nt][2], O[Mt][Nt][3]);
            *(u32x2*)(Pw + (Nt * 16 + l15) * 68 + Mt * 16 + quad * 4) = pk;  // [q][d]
        }
#pragma unroll
    for (int Nt = 0; Nt < 4; Nt++) {
        float ts = lrun[Nt];
        ts += __shfl_xor(ts, 16);
        ts += __shfl_xor(ts, 32);
        if (quad == 0) Ls[wv][Nt * 16 + l15] = ts;
    }
    __syncthreads();

    // Combine 4 wave-partials, normalize, write h [b][n][c] (single bf16)
    const int q = t >> 2, ds = (t & 3) * 16;
    const float l = Ls[0][q] + Ls[1][q] + Ls[2][q] + Ls[3][q];
    const float linv = 1.f / l;
    float acc[16];
#pragma unroll
    for (int e = 0; e < 16; e++) acc[e] = 0.f;
#pragma unroll
    for (int w = 0; w < 4; w++) {
        s16x8 a0 = *(const s16x8*)(Ps + w * 4352 + q * 68 + ds);
        s16x8 a1 = *(const s16x8*)(Ps + w * 4352 + q * 68 + ds + 8);
#pragma unroll
        for (int e = 0; e < 8; e++) {
            acc[e] += bf2f((ushort)a0[e]);
            acc[8 + e] += bf2f((ushort)a1[e]);
        }
    }
    u32x4 r0, r1;
#pragma unroll
    for (int e = 0; e < 4; e++) {
        r0[e] = cvtpk(acc[2 * e] * linv, acc[2 * e + 1] * linv);
        r1[e] = cvtpk(acc[8 + 2 * e] * linv, acc[9 + 2 * e] * linv);
    }
    const size_t go = ((size_t)b * 1024 + m0 + q) * 512 + h * 64 + ds;
    *(u32x4*)(ht + go) = r0;
    *(u32x4*)(ht + go + 8) = r1;
}

// ---------------------------------------------------------------------------
extern "C" void kernel_launch(void* const* d_in, const int* in_sizes, int n_in,
                              void* d_out, int out_size, void* d_ws, size_t ws_size,
                              hipStream_t stream) {
    (void)in_sizes; (void)n_in; (void)out_size; (void)ws_size;
    const float* x      = (const float*)d_in[0];
    const float* w_qkv  = (const float*)d_in[1];
    const float* w_proj = (const float*)d_in[2];
    const float* b_proj = (const float*)d_in[3];
    float* out = (float*)d_out;

    // workspace layout (bytes), total 35,651,584.  ht (8.39 MB) aliases
    // xt_h (dead after gemm_qkv); stream order makes this safe.
    char* ws = (char*)d_ws;
    ushort* xt_h = (ushort*)(ws);                       // 8,388,608 (later ht)
    ushort* wq_s = (ushort*)(ws + 8388608);             // 1,572,864
    ushort* wp_s = (ushort*)(ws + 9961472);             //   524,288
    ushort* qT   = (ushort*)(ws + 10485760);            // 8,388,608
    ushort* kT   = (ushort*)(ws + 18874368);            // 8,388,608
    ushort* vT   = (ushort*)(ws + 27262976);            // 8,388,608
    ushort* ht   = xt_h;                                // reuse (dead after qkv)

    prep<<<dim3(16, 8, 8), 256, 0, stream>>>(x, w_qkv, w_proj, xt_h,
                                             wq_s, wp_s);
    gemm_qkv<<<dim3(8, 12, 8), 256, 0, stream>>>(wq_s, xt_h, qT, kT, vT);
    attn_mfma<<<dim3(16, 64), 256, 0, stream>>>(qT, kT, vT, ht);
    gemm_proj<<<dim3(8, 8, 8), 256, 0, stream>>>(wp_s, xt_h, b_proj, out);
}

// Round 10
// 147.506 us; speedup vs baseline: 1.3549x; 1.3549x over previous
//
#include <hip/hip_runtime.h>
#include <math.h>

// ============================================================================
// Attention block (B=8, C=512, H=W=32, nh=8, hd=64) via bf16 MFMA + fp32-ish
// precision where it matters.  Round 20 = r18 RESTORED VERBATIM.
// r19 post-mortem: Mt-split S + PV-rotation spilled (WRITE 8->213MB, attn
// 45->97us).  SA+SB+extended-vf liveness ~260 regs > 256 @ 2 waves/EU --
// violated the r17 rule (reg estimates run 30-40 low).  Attn ledger now
// conclusive: r13/r15/r17/r19 all four occupancy/scheduling perturbations
// broke the 192-reg equilibrium and regressed.  This structure's honest
// operating point: 64-query blocks, wave-split keys, 2 waves/EU, ~45us.
//  - whole pipeline single x single bf16 (wq/wp/x single RNE planes; Q/K/V
//    bf16 epilogue rounding dominates error; absmax 0.00244, budget 7.3e-3).
//  - attn: bare v_exp_f32 (exp2 domain, Q pre-scale 0.125*log2e), deferred
//    cross-lane l-reduce, K prefetch inside S phase, V prefetch after PV,
//    setprio around MFMA clusters, XCD swizzle (FETCH 70->12MB).
//  - gemm_qkv/gemm_proj: gemm_core1 (1 MFMA/tile), fused prep.
// ============================================================================

typedef unsigned int u32;
typedef float  f32x4 __attribute__((ext_vector_type(4)));
typedef short  s16x8 __attribute__((ext_vector_type(8)));
typedef unsigned short u16x4 __attribute__((ext_vector_type(4)));
typedef unsigned int   u32x2 __attribute__((ext_vector_type(2)));
typedef unsigned int   u32x4 __attribute__((ext_vector_type(4)));

#define MFMA16(a, b, c) __builtin_amdgcn_mfma_f32_16x16x32_bf16(a, b, c, 0, 0, 0)

__device__ __forceinline__ ushort f2bf(float f) {  // RNE fp32->bf16 (scalar)
    u32 b = __float_as_uint(f);
    return (ushort)((b + 0x7FFFu + ((b >> 16) & 1u)) >> 16);
}
__device__ __forceinline__ float bf2f(ushort v) {
    return __uint_as_float(((u32)v) << 16);
}
// packed RNE fp32x2 -> bf16x2 (low16 = a, high16 = b)
__device__ __forceinline__ u32 cvtpk(float a, float b) {
    u32 r;
    asm("v_cvt_pk_bf16_f32 %0, %1, %2" : "=v"(r) : "v"(a), "v"(b));
    return r;
}

// ---------------------------------------------------------------------------
// prep: fused weight-convert + x transpose.
//  (a) wq, wp -> SINGLE RNE bf16 planes ([o][c] layout).  1024-block grid x
//      256 thr x 4 floats covers wq (786,432) + wp (262,144).
//  (b) x[b][c][n] fp32 -> xt SINGLE RNE bf16 [b][n][c] (64x64 transpose).
// ---------------------------------------------------------------------------
__global__ __launch_bounds__(256) void prep(
    const float* __restrict__ x, const float* __restrict__ wq,
    const float* __restrict__ wp, ushort* __restrict__ xh,
    ushort* __restrict__ wq_s, ushort* __restrict__ wp_s) {
    __shared__ __align__(16) ushort Th[64 * 72];
    const int t = threadIdx.x;

    // --- weight chunk (independent of x work; hides under LDS phase)
    {
        const int id = (blockIdx.z * 8 + blockIdx.y) * 16 + blockIdx.x;
        size_t base = ((size_t)id * 256 + t) * 4;
        const float* src; ushort* dst; size_t off;
        if (base < 786432) { src = wq; dst = wq_s; off = base; }
        else               { src = wp; dst = wp_s; off = base - 786432; }
        f32x4 v = *(const f32x4*)(src + off);
        u16x4 s;
#pragma unroll
        for (int e = 0; e < 4; e++) s[e] = f2bf(v[e]);
        *(u16x4*)(dst + off) = s;
    }

    // --- x transpose tile
    const int n0 = blockIdx.x * 64, c0 = blockIdx.y * 64, b = blockIdx.z;
    const int c = t >> 2, nseg = (t & 3) * 4;
    const float* src = x + ((size_t)b * 512 + c0 + c) * 1024 + n0;
#pragma unroll
    for (int i = 0; i < 4; i++) {
        f32x4 v = *(const f32x4*)(src + nseg + i * 16);
#pragma unroll
        for (int e = 0; e < 4; e++) {
            int nl = nseg + i * 16 + e;
            Th[nl * 72 + c] = f2bf(v[e]);
        }
    }
    __syncthreads();
#pragma unroll
    for (int i = 0; i < 2; i++) {
        int nl = i * 32 + (t >> 3);
        int u = t & 7;
        s16x8 vh = *(const s16x8*)(Th + nl * 72 + u * 8);
        size_t go = ((size_t)b * 1024 + n0 + nl) * 512 + c0 + u * 8;
        *(s16x8*)(xh + go) = vh;
    }
}

// ---------------------------------------------------------------------------
// single x single bf16 GEMM mainloop: 128x128 tile, BK=32, 1 MFMA/tile.
// acc[Mt][Nt]: D rows o = ohalf*64+Mt*16+quad*4+r, cols n = nhalf*64+Nt*16+l15.
// smem needs 10240 ushorts (20,480 B).
// ---------------------------------------------------------------------------
__device__ __forceinline__ void gemm_core1(
    const ushort* __restrict__ A_g, int arow0,
    const ushort* __restrict__ B_g, size_t brow0,
    ushort* smem, f32x4 (&acc)[4][4]) {
    const int t = threadIdx.x;
    ushort* As = smem;
    ushort* Bs = smem + 5120;
    const int ro = t >> 1, cs = (t & 1) << 4;
    const size_t ga = (size_t)(arow0 + ro) * 512 + cs;
    const size_t gb = (brow0 + ro) * 512 + cs;
    const int l15 = t & 15, quad = (t >> 4) & 3, wv = t >> 6;
    const int lra = (((wv >> 1) * 64) + l15) * 40 + quad * 8;
    const int lrb = (((wv & 1) * 64) + l15) * 40 + quad * 8;
    const int lw = ro * 40 + cs;

    s16x8 va0 = *(const s16x8*)(A_g + ga), va1 = *(const s16x8*)(A_g + ga + 8);
    s16x8 vb0 = *(const s16x8*)(B_g + gb), vb1 = *(const s16x8*)(B_g + gb + 8);

    for (int k0 = 0; k0 < 512; k0 += 32) {
        __syncthreads();
        *(s16x8*)(As + lw) = va0; *(s16x8*)(As + lw + 8) = va1;
        *(s16x8*)(Bs + lw) = vb0; *(s16x8*)(Bs + lw + 8) = vb1;
        const int kn = (k0 + 32) & 511;  // wraps to 0 on last iter (discarded)
        va0 = *(const s16x8*)(A_g + ga + kn); va1 = *(const s16x8*)(A_g + ga + kn + 8);
        vb0 = *(const s16x8*)(B_g + gb + kn); vb1 = *(const s16x8*)(B_g + gb + kn + 8);
        __syncthreads();
        s16x8 a[4], bb[4];
#pragma unroll
        for (int Mt = 0; Mt < 4; Mt++)
            a[Mt] = *(const s16x8*)(As + lra + Mt * 640);
#pragma unroll
        for (int Nt = 0; Nt < 4; Nt++)
            bb[Nt] = *(const s16x8*)(Bs + lrb + Nt * 640);
#pragma unroll
        for (int Mt = 0; Mt < 4; Mt++)
#pragma unroll
            for (int Nt = 0; Nt < 4; Nt++)
                acc[Mt][Nt] = MFMA16(a[Mt], bb[Nt], acc[Mt][Nt]);
    }
    __syncthreads();  // LDS free for epilogue reuse
}

// ---------------------------------------------------------------------------
// QKV GEMM (single x single).  o-halves (64 rows) align exactly to q/k/v
// roles: g = ot*2+ohalf, role = g%3 (0=q,1=k,2=v), head = g/3.  Q/K -> LDS
// transpose -> SINGLE bf16 plane [b][h][n][d] (Q pre-scaled by 0.125*log2e);
// V -> single bf16 [b][h][d][n].
// ---------------------------------------------------------------------------
__global__ __launch_bounds__(256) void gemm_qkv(
    const ushort* __restrict__ wq_s, const ushort* __restrict__ xt_h,
    ushort* __restrict__ qT, ushort* __restrict__ kT, ushort* __restrict__ vT) {
    __shared__ __align__(16) ushort smem[10240];
    f32x4 acc[4][4];
#pragma unroll
    for (int i = 0; i < 4; i++)
#pragma unroll
        for (int j = 0; j < 4; j++) acc[i][j] = (f32x4)0.0f;

    const int n0 = blockIdx.x * 128, o0 = blockIdx.y * 128, bz = blockIdx.z;
    gemm_core1(wq_s, o0, xt_h, (size_t)bz * 1024 + n0, smem, acc);

    const int t = threadIdx.x;
    const int l15 = t & 15, quad = (t >> 4) & 3, wv = t >> 6, lane = t & 63;
    const int g = blockIdx.y * 2 + (wv >> 1);
    const int role = g % 3, head = g / 3;
    const int nh = (wv & 1) * 64;
    const size_t hb = (size_t)bz * 8 + head;
    // Q scale folds attn's 1/sqrt(64) AND log2(e) so attn can use bare exp2.
    const float scale = (role == 0) ? 0.18033688011112042f : 1.0f;

    if (role < 2) {
        ushort* dst = (role == 0) ? qT : kT;
        ushort* T = smem + wv * 2304;                // per-wave [64 n][36] ushort
        const size_t rowbase = hb * 1024 + n0 + nh;  // pixel row index
#pragma unroll
        for (int sp = 0; sp < 2; sp++) {
#pragma unroll
            for (int Mti = 0; Mti < 2; Mti++)
#pragma unroll
                for (int Nt = 0; Nt < 4; Nt++) {
                    f32x4 v = acc[sp * 2 + Mti][Nt];
                    u32x2 pk;
                    pk.x = cvtpk(v[0] * scale, v[1] * scale);
                    pk.y = cvtpk(v[2] * scale, v[3] * scale);
                    *(u32x2*)(T + (Nt * 16 + l15) * 36 + Mti * 16 + quad * 4) = pk;
                }
            asm volatile("s_waitcnt lgkmcnt(0)" ::: "memory");
#pragma unroll
            for (int i = 0; i < 8; i++) {
                int nl = i * 8 + (lane >> 3);
                u16x4 vv = *(const u16x4*)(T + nl * 36 + (lane & 7) * 4);
                *(u16x4*)(dst + (rowbase + nl) * 64 + sp * 32 + (lane & 7) * 4) = vv;
            }
            asm volatile("s_waitcnt lgkmcnt(0)" ::: "memory");
        }
    } else {
        const size_t vb2 = hb * 64 * 1024 + (size_t)(n0 + nh);
#pragma unroll
        for (int Mt = 0; Mt < 4; Mt++)
#pragma unroll
            for (int Nt = 0; Nt < 4; Nt++)
#pragma unroll
                for (int r = 0; r < 4; r++)
                    vT[vb2 + (size_t)(Mt * 16 + quad * 4 + r) * 1024 + Nt * 16 + l15] =
                        f2bf(acc[Mt][Nt][r]);
    }
}

// ---------------------------------------------------------------------------
// Proj GEMM (single x single, gemm_core1): 1 MFMA/tile.
// out fp32 + bias, direct C/D stores.
// ---------------------------------------------------------------------------
__global__ __launch_bounds__(256) void gemm_proj(
    const ushort* __restrict__ wp_s, const ushort* __restrict__ ht,
    const float* __restrict__ bias, float* __restrict__ out) {
    __shared__ __align__(16) ushort smem[10240];
    f32x4 acc[4][4];
#pragma unroll
    for (int i = 0; i < 4; i++)
#pragma unroll
        for (int j = 0; j < 4; j++) acc[i][j] = (f32x4)0.0f;

    const int n0 = blockIdx.x * 128, o0 = blockIdx.y * 128, bz = blockIdx.z;
    gemm_core1(wp_s, o0, ht, (size_t)bz * 1024 + n0, smem, acc);

    const int t = threadIdx.x;
    const int l15 = t & 15, quad = (t >> 4) & 3, wv = t >> 6;
#pragma unroll
    for (int Mt = 0; Mt < 4; Mt++)
#pragma unroll
        for (int Nt = 0; Nt < 4; Nt++) {
            int ob = o0 + (wv >> 1) * 64 + Mt * 16 + quad * 4;
            int nn = n0 + (wv & 1) * 64 + Nt * 16 + l15;
#pragma unroll
            for (int r = 0; r < 4; r++)
                out[((size_t)bz * 512 + ob + r) * 1024 + nn] = acc[Mt][Nt][r] + bias[ob + r];
        }
}

// ---------------------------------------------------------------------------
// Flash attention (r16/r18 form, measured 45us): 64-query blocks, wave-split
// keys (wave w owns kt=w*4..w*4+3), in-block combine (ONE barrier).
// launch_bounds (256,2) -- ~190 live regs/wave is the honest footprint.
// Bare v_exp_f32; deferred cross-lane l-reduce; K prefetch inside S phase;
// V prefetch after PV; setprio around MFMA clusters.
// Grid 1024 blocks; LDS Pw 4x[64][68] (reused for O partials) + Ls 1KB.
// ---------------------------------------------------------------------------
__global__ __launch_bounds__(256, 2) void attn_mfma(
    const ushort* __restrict__ qT, const ushort* __restrict__ kT,
    const ushort* __restrict__ vT, ushort* __restrict__ ht) {
    __shared__ __align__(16) ushort Ps[4 * 4352];  // per-wave [64 q][68]
    __shared__ float Ls[4][64];
    const int t = threadIdx.x;
    // XCD swizzle: dispatch round-robins blocks over 8 XCDs; remap so each
    // XCD owns 8 consecutive bh (16 qt each) -> K/V slice (2MB) L2-resident.
    const int id = blockIdx.x + (blockIdx.y << 4);
    const int swz = (id & 7) * 128 + (id >> 3);
    const int qt = swz & 15, bh = swz >> 4;
    const int b = bh >> 3, h = bh & 7;
    const int m0 = qt * 64;
    const int l15 = t & 15, quad = (t >> 4) & 3, wv = t >> 6;

    // All 64 block-queries in registers: 4 Nt tiles x 2 ks (single bf16)
    s16x8 qf[4][2];
#pragma unroll
    for (int Nt = 0; Nt < 4; Nt++) {
        const size_t qb = ((size_t)bh * 1024 + m0 + Nt * 16 + l15) * 64 + quad * 8;
        qf[Nt][0] = *(const s16x8*)(qT + qb);
        qf[Nt][1] = *(const s16x8*)(qT + qb + 32);
    }

    f32x4 O[4][4];  // [Mt: d-tile][Nt: q-tile]
#pragma unroll
    for (int i = 0; i < 4; i++)
#pragma unroll
        for (int j = 0; j < 4; j++) O[i][j] = (f32x4)0.0f;
    // Per-lane l partials (this lane's k-subset only; cross-lane reduce at end)
    float lrun[4] = {0.f, 0.f, 0.f, 0.f};

    const ushort* kb = kT + (size_t)bh * 65536;
    const ushort* vb = vT + (size_t)bh * 65536;
    ushort* Pw = Ps + wv * 4352;

    // Prologue: K/V fragments for tile 0 (wave-private, disjoint slices)
    s16x8 kf[2][4], vf[2][4];
    {
        const int kt = wv * 4;
        const size_t kbase = (size_t)kt * 4096 + l15 * 64 + quad * 8;
        const size_t vbase = (size_t)l15 * 1024 + kt * 64 + quad * 8;
#pragma unroll
        for (int ks = 0; ks < 2; ks++)
#pragma unroll
            for (int Mt = 0; Mt < 4; Mt++) {
                kf[ks][Mt] = *(const s16x8*)(kb + kbase + Mt * 1024 + ks * 32);
                vf[ks][Mt] = *(const s16x8*)(vb + vbase + Mt * 16384 + ks * 32);
            }
    }

#pragma unroll 1
    for (int i = 0; i < 4; i++) {
        const int ktn = wv * 4 + i + 1;  // next wave-private key tile

        // S in two query-pair phases (halves S register pressure)
#pragma unroll
        for (int g2 = 0; g2 < 2; g2++) {
            f32x4 S[4][2];
#pragma unroll
            for (int a = 0; a < 4; a++) { S[a][0] = (f32x4)0.0f; S[a][1] = (f32x4)0.0f; }
            __builtin_amdgcn_s_setprio(1);
#pragma unroll
            for (int ks = 0; ks < 2; ks++)
#pragma unroll
                for (int Mt = 0; Mt < 4; Mt++)
#pragma unroll
                    for (int n2 = 0; n2 < 2; n2++)
                        S[Mt][n2] = MFMA16(kf[ks][Mt], qf[g2 * 2 + n2][ks], S[Mt][n2]);
            __builtin_amdgcn_s_setprio(0);

            // kf regs dead after the g2==1 MFMA cluster above: issue next
            // tile's K loads NOW (covered by exp+pack below and PV).
            if (g2 == 1 && i < 3) {
                const size_t kbase = (size_t)ktn * 4096 + l15 * 64 + quad * 8;
#pragma unroll
                for (int ks = 0; ks < 2; ks++)
#pragma unroll
                    for (int Mt = 0; Mt < 4; Mt++)
                        kf[ks][Mt] = *(const s16x8*)(kb + kbase + Mt * 1024 + ks * 32);
            }

#pragma unroll
            for (int n2 = 0; n2 < 2; n2++) {
                // exp2 (Q pre-scaled by log2e); bare v_exp_f32
#pragma unroll
                for (int Mt = 0; Mt < 4; Mt++)
#pragma unroll
                    for (int r = 0; r < 4; r++)
                        S[Mt][n2][r] = __builtin_amdgcn_exp2f(S[Mt][n2][r]);
                // lane-local tree sum (depth 4); NO cross-lane shuffle here
                float s0 = (S[0][n2][0] + S[0][n2][1]) + (S[0][n2][2] + S[0][n2][3]);
                float s1 = (S[1][n2][0] + S[1][n2][1]) + (S[1][n2][2] + S[1][n2][3]);
                float s2 = (S[2][n2][0] + S[2][n2][1]) + (S[2][n2][2] + S[2][n2][3]);
                float s3 = (S[3][n2][0] + S[3][n2][1]) + (S[3][n2][2] + S[3][n2][3]);
                lrun[g2 * 2 + n2] += (s0 + s1) + (s2 + s3);
            }
#pragma unroll
            for (int Mt = 0; Mt < 4; Mt++)
#pragma unroll
                for (int n2 = 0; n2 < 2; n2++) {
                    u32x2 pb;
                    pb.x = cvtpk(S[Mt][n2][0], S[Mt][n2][1]);
                    pb.y = cvtpk(S[Mt][n2][2], S[Mt][n2][3]);
                    *(u32x2*)(Pw + ((g2 * 2 + n2) * 16 + l15) * 68 + Mt * 16 + quad * 4) = pb;
                }
        }

        // PV: O += V @ P (wave-private P, no barrier)
#pragma unroll
        for (int ks = 0; ks < 2; ks++) {
            s16x8 pf[4];
#pragma unroll
            for (int Nt = 0; Nt < 4; Nt++)
                pf[Nt] = *(const s16x8*)(Pw + (Nt * 16 + l15) * 68 + ks * 32 + quad * 8);
            __builtin_amdgcn_s_setprio(1);
#pragma unroll
            for (int Mt = 0; Mt < 4; Mt++)
#pragma unroll
                for (int Nt = 0; Nt < 4; Nt++)
                    O[Mt][Nt] = MFMA16(vf[ks][Mt], pf[Nt], O[Mt][Nt]);
            __builtin_amdgcn_s_setprio(0);
        }

        // Prefetch V for next tile (vf regs dead after PV MFMAs issued);
        // latency hides under next iteration's S phase.
        if (i < 3) {
            const size_t vbase = (size_t)l15 * 1024 + ktn * 64 + quad * 8;
#pragma unroll
            for (int ks = 0; ks < 2; ks++)
#pragma unroll
                for (int Mt = 0; Mt < 4; Mt++)
                    vf[ks][Mt] = *(const s16x8*)(vb + vbase + Mt * 16384 + ks * 32);
        }
    }

    // Wave partials -> LDS (bf16 O over the dead P region; fp32 l).
    // Cross-lane l reduce deferred to here: 2 shuffle hops once per kernel.
#pragma unroll
    for (int Mt = 0; Mt < 4; Mt++)
#pragma unroll
        for (int Nt = 0; Nt < 4; Nt++) {
            u32x2 pk;
            pk.x = cvtpk(O[Mt][Nt][0], O[Mt][Nt][1]);
            pk.y = cvtpk(O[Mt][Nt][2], O[Mt][Nt][3]);
            *(u32x2*)(Pw + (Nt * 16 + l15) * 68 + Mt * 16 + quad * 4) = pk;  // [q][d]
        }
#pragma unroll
    for (int Nt = 0; Nt < 4; Nt++) {
        float ts = lrun[Nt];
        ts += __shfl_xor(ts, 16);
        ts += __shfl_xor(ts, 32);
        if (quad == 0) Ls[wv][Nt * 16 + l15] = ts;
    }
    __syncthreads();

    // Combine 4 wave-partials, normalize, write h [b][n][c] (single bf16)
    const int q = t >> 2, ds = (t & 3) * 16;
    const float l = Ls[0][q] + Ls[1][q] + Ls[2][q] + Ls[3][q];
    const float linv = 1.f / l;
    float acc[16];
#pragma unroll
    for (int e = 0; e < 16; e++) acc[e] = 0.f;
#pragma unroll
    for (int w = 0; w < 4; w++) {
        s16x8 a0 = *(const s16x8*)(Ps + w * 4352 + q * 68 + ds);
        s16x8 a1 = *(const s16x8*)(Ps + w * 4352 + q * 68 + ds + 8);
#pragma unroll
        for (int e = 0; e < 8; e++) {
            acc[e] += bf2f((ushort)a0[e]);
            acc[8 + e] += bf2f((ushort)a1[e]);
        }
    }
    u32x4 r0, r1;
#pragma unroll
    for (int e = 0; e < 4; e++) {
        r0[e] = cvtpk(acc[2 * e] * linv, acc[2 * e + 1] * linv);
        r1[e] = cvtpk(acc[8 + 2 * e] * linv, acc[9 + 2 * e] * linv);
    }
    const size_t go = ((size_t)b * 1024 + m0 + q) * 512 + h * 64 + ds;
    *(u32x4*)(ht + go) = r0;
    *(u32x4*)(ht + go + 8) = r1;
}

// ---------------------------------------------------------------------------
extern "C" void kernel_launch(void* const* d_in, const int* in_sizes, int n_in,
                              void* d_out, int out_size, void* d_ws, size_t ws_size,
                              hipStream_t stream) {
    (void)in_sizes; (void)n_in; (void)out_size; (void)ws_size;
    const float* x      = (const float*)d_in[0];
    const float* w_qkv  = (const float*)d_in[1];
    const float* w_proj = (const float*)d_in[2];
    const float* b_proj = (const float*)d_in[3];
    float* out = (float*)d_out;

    // workspace layout (bytes), total 35,651,584.  ht (8.39 MB) aliases
    // xt_h (dead after gemm_qkv); stream order makes this safe.
    char* ws = (char*)d_ws;
    ushort* xt_h = (ushort*)(ws);                       // 8,388,608 (later ht)
    ushort* wq_s = (ushort*)(ws + 8388608);             // 1,572,864
    ushort* wp_s = (ushort*)(ws + 9961472);             //   524,288
    ushort* qT   = (ushort*)(ws + 10485760);            // 8,388,608
    ushort* kT   = (ushort*)(ws + 18874368);            // 8,388,608
    ushort* vT   = (ushort*)(ws + 27262976);            // 8,388,608
    ushort* ht   = xt_h;                                // reuse (dead after qkv)

    prep<<<dim3(16, 8, 8), 256, 0, stream>>>(x, w_qkv, w_proj, xt_h,
                                             wq_s, wp_s);
    gemm_qkv<<<dim3(8, 12, 8), 256, 0, stream>>>(wq_s, xt_h, qT, kT, vT);
    attn_mfma<<<dim3(16, 64), 256, 0, stream>>>(qT, kT, vT, ht);
    gemm_proj<<<dim3(8, 4, 8), 256, 0, stream>>>(wp_s, xt_h, b_proj, out);
}